// Round 5
// baseline (32.584 us; speedup 1.0000x reference)
//
#include <hip/hip_runtime.h>

// Problem constants (from reference): B=32, C=4, L=512
constexpr int B = 32;
constexpr int C = 4;
constexpr int L = 512;
constexpr int THREADS = 256;       // 4 waves
constexpr int ROWS_PER_WAVE = 4;
constexpr int RPB = 4 * ROWS_PER_WAVE;  // 16 rows per block
constexpr int CHUNKS = L / RPB;         // 32 row-chunks per plane

// Unaligned-tolerant 16B load (ligand side is only dword-aligned).
__device__ inline float4 ld4u(const float* p) {
    float4 v;
    __builtin_memcpy(&v, p, sizeof(float4));
    return v;
}

// Stage 1: one block per (row-chunk, plane). blockIdx.x = chunk (FASTEST) so
// concurrently-resident blocks read a contiguous few-plane region (near-
// sequential chip-wide DRAM order). Each block streams a 32KB contiguous slab
// of each array. Branch-free: all loads issue before any use (max MLP);
// invalid lanes clamp addresses in-bounds and are masked at combine time.
__global__ __launch_bounds__(THREADS)
void imgmul_stage1(const float* __restrict__ receptor,
                   const float* __restrict__ ligand,
                   const int* __restrict__ T,
                   float* __restrict__ partials)
{
    const int chunk = blockIdx.x;        // 0..CHUNKS-1
    const int bc    = blockIdx.y;        // 0..B*C-1
    const int b     = bc >> 2;           // C == 4
    const int dx = T[2 * b + 0];
    const int dy = T[2 * b + 1];

    const int x0 = dx > 0 ? dx : 0;
    const int x1 = (L + dx) < L ? (L + dx) : L;
    const int y0 = dy > 0 ? dy : 0;
    const int y1 = (L + dy) < L ? (L + dy) : L;

    const int ya    = (y0 + 3) & ~3;     // receptor-aligned quad base
    const int head  = ya - y0;           // 0..3
    const int nq    = (y1 - ya) >> 2;    // 63..128 (|dy| <= 256)
    const int rem   = (y1 - ya) & 3;     // 0..3
    const int ytail = ya + 4 * nq;
    const int nq2   = nq - 64;           // -1..64

    const size_t plane = (size_t)bc * (L * L);
    const float* rec = receptor + plane;
    const float* lig = ligand + plane;

    const int wave = threadIdx.x >> 6;
    const int lane = threadIdx.x & 63;
    const int rbase = chunk * RPB;

    // Per-lane column coordinates (shared by all rows).
    const int  yq0 = ya + 4 * lane;                    // always valid (nq >= 63... lane 63 needs nq>63)
    const bool v0  = lane < nq;                        // guard lane 63 when nq==63
    const int  yq0c = v0 ? yq0 : ya;
    const bool v1  = lane < nq2;
    const int  yq1 = v1 ? (ya + 4 * (64 + lane)) : ya;
    const bool vh  = lane < head;
    const int  yh  = vh ? (y0 + lane) : y0;
    const bool vt  = lane < rem;
    const int  yt  = vt ? (ytail + lane) : y0;

    // Row coordinates: wave w handles rows rbase + w + 4*r, r = 0..3.
    bool vrow[ROWS_PER_WAVE];
    const float* rrow[ROWS_PER_WAVE];
    const float* lrow[ROWS_PER_WAVE];
    #pragma unroll
    for (int r = 0; r < ROWS_PER_WAVE; ++r) {
        const int x  = rbase + wave + 4 * r;
        const bool v = (x >= x0) & (x < x1);
        vrow[r] = v;
        const int xc = v ? x : x0;
        rrow[r] = rec + (size_t)xc * L;
        lrow[r] = lig + (size_t)(xc - dx) * L - dy;  // lrow[y] = lig[x-dx][y-dy]
    }

    // ---- Issue ALL loads (single basic block) ----
    float4 rv0[ROWS_PER_WAVE], lv0[ROWS_PER_WAVE];
    float4 rv1[ROWS_PER_WAVE], lv1[ROWS_PER_WAVE];
    float rh[ROWS_PER_WAVE], lh[ROWS_PER_WAVE];
    float rt[ROWS_PER_WAVE], lt[ROWS_PER_WAVE];
    #pragma unroll
    for (int r = 0; r < ROWS_PER_WAVE; ++r) {
        rv0[r] = *reinterpret_cast<const float4*>(rrow[r] + yq0c);
        lv0[r] = ld4u(lrow[r] + yq0c);
        rv1[r] = *reinterpret_cast<const float4*>(rrow[r] + yq1);
        lv1[r] = ld4u(lrow[r] + yq1);
        rh[r] = rrow[r][yh];  lh[r] = lrow[r][yh];
        rt[r] = rrow[r][yt];  lt[r] = lrow[r][yt];
    }

    // ---- Arithmetic + masked combine ----
    float acc = 0.0f;
    #pragma unroll
    for (int r = 0; r < ROWS_PER_WAVE; ++r) {
        float d0 = rv0[r].x * lv0[r].x;
        d0 = fmaf(rv0[r].y, lv0[r].y, d0);
        d0 = fmaf(rv0[r].z, lv0[r].z, d0);
        d0 = fmaf(rv0[r].w, lv0[r].w, d0);
        float d1 = rv1[r].x * lv1[r].x;
        d1 = fmaf(rv1[r].y, lv1[r].y, d1);
        d1 = fmaf(rv1[r].z, lv1[r].z, d1);
        d1 = fmaf(rv1[r].w, lv1[r].w, d1);
        float row = (v0 ? d0 : 0.0f) + (v1 ? d1 : 0.0f);
        row += vh ? rh[r] * lh[r] : 0.0f;
        row += vt ? rt[r] * lt[r] : 0.0f;
        acc += vrow[r] ? row : 0.0f;
    }

    // ---- Wave reduce, then cross-wave via LDS ----
    #pragma unroll
    for (int off = 32; off > 0; off >>= 1)
        acc += __shfl_down(acc, off, 64);

    __shared__ float wsum[THREADS / 64];
    if (lane == 0) wsum[wave] = acc;
    __syncthreads();

    if (threadIdx.x == 0)
        partials[bc * CHUNKS + chunk] = wsum[0] + wsum[1] + wsum[2] + wsum[3];
}

// Stage 2: out[bc] = sum of its 32 partials (one wave per output).
__global__ __launch_bounds__(64)
void imgmul_stage2(const float* __restrict__ partials, float* __restrict__ out)
{
    const int bc = blockIdx.x;
    const int lane = threadIdx.x & 63;
    float v = (lane < CHUNKS) ? partials[bc * CHUNKS + lane] : 0.0f;
    #pragma unroll
    for (int off = 32; off > 0; off >>= 1)
        v += __shfl_down(v, off, 64);
    if (lane == 0) out[bc] = v;
}

extern "C" void kernel_launch(void* const* d_in, const int* in_sizes, int n_in,
                              void* d_out, int out_size, void* d_ws, size_t ws_size,
                              hipStream_t stream)
{
    const float* receptor = (const float*)d_in[0];
    const float* ligand   = (const float*)d_in[1];
    const int*   T        = (const int*)d_in[2];
    float* out      = (float*)d_out;
    float* partials = (float*)d_ws;      // B*C*CHUNKS = 4096 floats of scratch

    imgmul_stage1<<<dim3(CHUNKS, B * C), dim3(THREADS), 0, stream>>>(
        receptor, ligand, T, partials);
    imgmul_stage2<<<dim3(B * C), dim3(64), 0, stream>>>(partials, out);
}